// Round 1
// 275.371 us; speedup vs baseline: 1.1575x; 1.1575x over previous
//
#include <hip/hip_runtime.h>

#define NPTS   16384
#define KCODES 8192
#define DDIM   256
#define HWSZ   1024
#define CHW    (DDIM * HWSZ)          // 262144
#define OUT_ELEMS 4194304
#define LOSS_OFF  OUT_ELEMS
#define IDX_OFF   (OUT_ELEMS + 1)

#define PTB   64                 // points per block
#define CTILE 128                // codes per tile
#define KC    64                 // k per staged chunk
#define NIT   256                // 64 tiles x 4 chunks; image index == it
#define XPITCH 264               // x f16 pitch (528 B = 4 mod 32 banks -> 2-way, free)

typedef _Float16 half_t;
typedef __attribute__((ext_vector_type(8))) _Float16 half8;
typedef __attribute__((ext_vector_type(4))) float     v4f;

union HU { _Float16 h; unsigned short u; };

// ws layout: ehi[256 images][128 codes][64 ushort] (16 KB/image, 4 MB),
//            elo same (4 MB), se[8192] f32. Images pre-swizzled: row r,
//            16B-block kb stored at block (kb ^ (r&7)) -> LDS fragment reads
//            are 2-way bank-aliased with zero padding, and staging is
//            a pure linear DMA via global_load_lds (no VALU, no conflicts).
#define EHI_WORDS  (256 * 8192)                 // ushorts
#define SE_OFF_B   (2 * EHI_WORDS * 2)          // byte offset of se[] in ws

#define GLD16(gp, lp) __builtin_amdgcn_global_load_lds( \
    (const __attribute__((address_space(1))) unsigned int*)(gp), \
    (__attribute__((address_space(3))) unsigned int*)(lp), 16, 0, 0)

// ---- prep: split emb to f16 hi/lo (bit-identical formula to R7 staging),
// ---- pre-swizzled image layout, plus se[k] = ||e_k||^2 (fp32) ----
// Coverage: 256 blocks x 4 waves = 1024 waves x 8 codes = 8192 codes.
// (R8 BUG: launched 32 blocks -> only codes 0..1023 prepped, rest poison.)
__global__ void prep_kernel(const float* __restrict__ emb,
                            unsigned short* __restrict__ ehi,
                            unsigned short* __restrict__ elo,
                            float* __restrict__ se)
{
    const int gw   = (blockIdx.x * 256 + threadIdx.x) >> 6;   // 0..1023
    const int lane = threadIdx.x & 63;
    for (int i = 0; i < 8; ++i) {
        const int c = gw * 8 + i;                             // code 0..8191
        const float4 v = *(const float4*)(emb + (size_t)c * DDIM + lane * 4);
        float ps = v.x * v.x;
        ps = fmaf(v.y, v.y, ps); ps = fmaf(v.z, v.z, ps); ps = fmaf(v.w, v.w, ps);
        float tot = ps;
        #pragma unroll
        for (int off = 1; off < 64; off <<= 1) tot += __shfl_xor(tot, off);
        if (lane == 0) se[c] = tot;
        const float E0 = v.x * 64.f, E1 = v.y * 64.f, E2 = v.z * 64.f, E3 = v.w * 64.f;
        const half_t h0 = (half_t)E0, h1 = (half_t)E1, h2 = (half_t)E2, h3 = (half_t)E3;
        const half_t l0 = (half_t)((E0 - (float)h0) * 2048.f);
        const half_t l1 = (half_t)((E1 - (float)h1) * 2048.f);
        const half_t l2 = (half_t)((E2 - (float)h2) * 2048.f);
        const half_t l3 = (half_t)((E3 - (float)h3) * 2048.f);
        HU a0, a1, a2, a3, b0, b1, b2, b3;
        a0.h = h0; a1.h = h1; a2.h = h2; a3.h = h3;
        b0.h = l0; b1.h = l1; b2.h = l2; b3.h = l3;
        const unsigned int uh0 = (unsigned)a0.u | ((unsigned)a1.u << 16);
        const unsigned int uh1 = (unsigned)a2.u | ((unsigned)a3.u << 16);
        const unsigned int ul0 = (unsigned)b0.u | ((unsigned)b1.u << 16);
        const unsigned int ul1 = (unsigned)b2.u | ((unsigned)b3.u << 16);
        const int ck = lane >> 4;                 // chunk 0..3 (k block of 64)
        const int kb = (lane & 15) >> 1;          // 16B block within row, 0..7
        const int hf = lane & 1;                  // half-block
        const int T = c >> 7, r = c & 127;
        const size_t base = (((size_t)(T * 4 + ck) * 128 + r) * 64)
                          + (size_t)((kb ^ (r & 7)) * 8) + hf * 4;
        *(unsigned int*)&ehi[base]     = uh0;
        *(unsigned int*)&ehi[base + 2] = uh1;
        *(unsigned int*)&elo[base]     = ul0;
        *(unsigned int*)&elo[base + 2] = ul1;
    }
}

// m = x.e via 3 f16 MFMAs (exact pow2 scalings, R7-identical):
//   m = (hh + (xh.el + xl.eh)*2^-11) / 64
// dist = fl(fl(s+se) - 2m) fp32, lowest-index tie-break (proven R1-R7).
// R9: A-fragments (x hi/lo) hoisted to 128 VGPRs for the whole main loop —
//     they are tile-invariant, and re-reading them from LDS was half the
//     LDS read traffic (kernel was LDS-BW-bound: ~2050 LDS cy/iter vs
//     931 MFMA cy/iter). ck-loop unrolled so the register array is
//     statically indexed (runtime index => scratch).
// NOTE: never pass a second __launch_bounds__ arg on this toolchain (R4).
__launch_bounds__(512)
__global__ void vq_kernel(const float* __restrict__ x,
                          const unsigned short* __restrict__ ehi,
                          const unsigned short* __restrict__ elo,
                          const float* __restrict__ wse,
                          const float* __restrict__ emb,
                          float* __restrict__ out)
{
    __shared__ __align__(16) unsigned short ldsXH[PTB][XPITCH];   // 33792 B
    __shared__ __align__(16) unsigned short ldsXL[PTB][XPITCH];   // 33792 B
    __shared__ __align__(16) unsigned short ldsEH[2][8192];       // 32768 B
    __shared__ __align__(16) unsigned short ldsEL[2][8192];       // 32768 B
    __shared__ float  ldsRS[8][65];
    __shared__ float  ldsS[PTB];
    __shared__ float  ldsFD[8][32];
    __shared__ int    ldsFI[8][32];
    __shared__ int    ldsI[PTB];
    __shared__ double ldsL[8];

    const int t    = threadIdx.x;
    const int lane = t & 63;
    const int w    = t >> 6;          // 0..7
    const int n0   = blockIdx.x * PTB;
    const int b    = n0 / HWSZ;
    const int hw0  = n0 % HWSZ;
    const float* xs = x + (size_t)b * CHW + hw0;   // xs[c*HWSZ + p]

    // ---- e-chunk DMA staging: 32 KB/iter; waves 0-3 hi, 4-7 lo; 4x1KB calls ----
    const int part = (w & 3) * 4096;               // byte sub-range
    #define STAGE(img, buf) do { \
        const char* _g = (const char*)((w < 4) ? ehi : elo) \
                       + (size_t)(img) * 16384 + part + lane * 16; \
        char* _l = (char*)((w < 4) ? ldsEH[buf] : ldsEL[buf]) + part; \
        GLD16(_g,          _l); \
        GLD16(_g + 1024,   _l + 1024); \
        GLD16(_g + 2048,   _l + 2048); \
        GLD16(_g + 3072,   _l + 3072); \
    } while (0)

    STAGE(0, 0);   // bootstrap chunk 0 (drained by first loop barrier)

    // ---- prologue: stage x split hi/lo (f16), accumulate s[p]=||x_p||^2 ----
    {
        const int p   = t & 63;
        const int seg = t >> 6;
        float a = 0.f;
        for (int i = 0; i < 32; ++i) {
            const int c = seg * 32 + i;
            const float v = xs[(size_t)c * HWSZ + p];
            const half_t hh = (half_t)v;
            const half_t hl = (half_t)((v - (float)hh) * 2048.0f);
            HU u0; u0.h = hh; ldsXH[p][c] = u0.u;
            HU u1; u1.h = hl; ldsXL[p][c] = u1.u;
            a = fmaf(v, v, a);
        }
        ldsRS[seg][p] = a;
    }
    __syncthreads();
    if (t < PTB) {
        float s = 0.f;
        for (int g = 0; g < 8; ++g) s += ldsRS[g][t];
        ldsS[t] = s;
    }
    __syncthreads();

    const int h32 = (w & 1) * 32;     // pt-half base row
    const int q32 = (w >> 1) * 32;    // code-quarter base within tile
    const int ln  = lane & 15;
    const int qd  = lane >> 4;        // 0..3

    float s_frag[8];
    #pragma unroll
    for (int pbi = 0; pbi < 2; ++pbi)
        #pragma unroll
        for (int r = 0; r < 4; ++r)
            s_frag[pbi * 4 + r] = ldsS[h32 + pbi * 16 + qd * 4 + r];

    // ---- A-fragment hoist: this wave's 32 x-rows, full K=256, hi+lo ----
    // 32 half8 = 128 VGPRs; tile-invariant, read ONCE (was re-read 64x).
    half8 aH[2][4][2], aL[2][4][2];   // [pt-block][ck][kk]
    #pragma unroll
    for (int pb = 0; pb < 2; ++pb)
        #pragma unroll
        for (int ck = 0; ck < 4; ++ck)
            #pragma unroll
            for (int kk = 0; kk < 2; ++kk) {
                const int ka = ck * KC + kk * 32 + qd * 8;
                aH[pb][ck][kk] = *(const half8*)&ldsXH[h32 + pb * 16 + ln][ka];
                aL[pb][ck][kk] = *(const half8*)&ldsXL[h32 + pb * 16 + ln][ka];
            }

    float best_d[8]; int best_i[8];
    #pragma unroll
    for (int i = 0; i < 8; ++i) { best_d[i] = 3.4e38f; best_i[i] = 0; }

    v4f acc_hh[2][2], acc_hl[2][2];
    float se0 = 0.f, se1 = 0.f;

    for (int tile = 0; tile < 64; ++tile) {
        #pragma unroll
        for (int i = 0; i < 2; ++i)
            #pragma unroll
            for (int j = 0; j < 2; ++j)
                #pragma unroll
                for (int r = 0; r < 4; ++r) { acc_hh[i][j][r] = 0.f; acc_hl[i][j][r] = 0.f; }
        #pragma unroll
        for (int ck = 0; ck < 4; ++ck) {
            const int it = tile * 4 + ck;
            __syncthreads();   // buf[ck&1] DMA drained; prior readers of other buf done
            if (it + 1 < NIT) STAGE(it + 1, (ck + 1) & 1);   // async under compute
            if (ck == 2) {     // prefetch se for this tile's finalize (L2-hot 32 KB)
                const int tb2 = tile * CTILE;
                se0 = wse[tb2 + q32 + ln];
                se1 = wse[tb2 + q32 + 16 + ln];
            }
            // ---- MFMA: 32 pts x 32 codes, K=64 via 2 K32 steps x 3 splits x 2x2 ----
            #pragma unroll
            for (int kk = 0; kk < 2; ++kk) {
                const int swz = ((kk * 4 + qd) ^ (ln & 7)) * 8;  // swizzled e block
                const int rL  = (q32 + ln) * 64;
                const int rH  = (q32 + 16 + ln) * 64;
                const half8 bh0 = *(const half8*)&ldsEH[ck & 1][rL + swz];
                const half8 bh1 = *(const half8*)&ldsEH[ck & 1][rH + swz];
                const half8 bl0 = *(const half8*)&ldsEL[ck & 1][rL + swz];
                const half8 bl1 = *(const half8*)&ldsEL[ck & 1][rH + swz];
                acc_hh[0][0] = __builtin_amdgcn_mfma_f32_16x16x32_f16(aH[0][ck][kk], bh0, acc_hh[0][0], 0, 0, 0);
                acc_hh[0][1] = __builtin_amdgcn_mfma_f32_16x16x32_f16(aH[0][ck][kk], bh1, acc_hh[0][1], 0, 0, 0);
                acc_hh[1][0] = __builtin_amdgcn_mfma_f32_16x16x32_f16(aH[1][ck][kk], bh0, acc_hh[1][0], 0, 0, 0);
                acc_hh[1][1] = __builtin_amdgcn_mfma_f32_16x16x32_f16(aH[1][ck][kk], bh1, acc_hh[1][1], 0, 0, 0);
                acc_hl[0][0] = __builtin_amdgcn_mfma_f32_16x16x32_f16(aH[0][ck][kk], bl0, acc_hl[0][0], 0, 0, 0);
                acc_hl[0][1] = __builtin_amdgcn_mfma_f32_16x16x32_f16(aH[0][ck][kk], bl1, acc_hl[0][1], 0, 0, 0);
                acc_hl[1][0] = __builtin_amdgcn_mfma_f32_16x16x32_f16(aH[1][ck][kk], bl0, acc_hl[1][0], 0, 0, 0);
                acc_hl[1][1] = __builtin_amdgcn_mfma_f32_16x16x32_f16(aH[1][ck][kk], bl1, acc_hl[1][1], 0, 0, 0);
                acc_hl[0][0] = __builtin_amdgcn_mfma_f32_16x16x32_f16(aL[0][ck][kk], bh0, acc_hl[0][0], 0, 0, 0);
                acc_hl[0][1] = __builtin_amdgcn_mfma_f32_16x16x32_f16(aL[0][ck][kk], bh1, acc_hl[0][1], 0, 0, 0);
                acc_hl[1][0] = __builtin_amdgcn_mfma_f32_16x16x32_f16(aL[1][ck][kk], bh0, acc_hl[1][0], 0, 0, 0);
                acc_hl[1][1] = __builtin_amdgcn_mfma_f32_16x16x32_f16(aL[1][ck][kk], bh1, acc_hl[1][1], 0, 0, 0);
            }
            // ---- tile finalize: dist = fl(fl(s+se) - 2m), ascending code order ----
            if (ck == 3) {
                const int tb = tile * CTILE;
                #pragma unroll
                for (int csi = 0; csi < 2; ++csi) {
                    const float se   = csi ? se1 : se0;
                    const int   code = tb + q32 + csi * 16 + ln;
                    #pragma unroll
                    for (int pbi = 0; pbi < 2; ++pbi)
                        #pragma unroll
                        for (int r = 0; r < 4; ++r) {
                            const float m  = fmaf(acc_hl[pbi][csi][r], 4.8828125e-4f,
                                                  acc_hh[pbi][csi][r]) * 0.015625f;
                            const float T  = s_frag[pbi * 4 + r] + se;
                            const float dd = fmaf(-2.0f, m, T);
                            const int   s  = pbi * 4 + r;
                            if (dd < best_d[s]) { best_d[s] = dd; best_i[s] = code; }
                        }
                }
            }
        }
    }

    // ---- argmin reduce: butterfly over the 16-lane col group (lexicographic) ----
    #pragma unroll
    for (int off = 1; off < 16; off <<= 1) {
        #pragma unroll
        for (int s = 0; s < 8; ++s) {
            const float d2 = __shfl_xor(best_d[s], off);
            const int   i2 = __shfl_xor(best_i[s], off);
            if (d2 < best_d[s] || (d2 == best_d[s] && i2 < best_i[s])) {
                best_d[s] = d2; best_i[s] = i2;
            }
        }
    }
    if (ln == 0) {
        #pragma unroll
        for (int pbi = 0; pbi < 2; ++pbi)
            #pragma unroll
            for (int r = 0; r < 4; ++r) {
                ldsFD[w][pbi * 16 + qd * 4 + r] = best_d[pbi * 4 + r];
                ldsFI[w][pbi * 16 + qd * 4 + r] = best_i[pbi * 4 + r];
            }
    }
    __syncthreads();
    if (t < PTB) {
        const int hh  = t >> 5;
        const int r32 = t & 31;
        float bd = 3.4e38f; int bi = 0;
        #pragma unroll
        for (int qq = 0; qq < 4; ++qq) {
            const int wv = hh + qq * 2;
            const float d2 = ldsFD[wv][r32];
            const int   i2 = ldsFI[wv][r32];
            if (d2 < bd || (d2 == bd && i2 < bi)) { bd = d2; bi = i2; }
        }
        ldsI[t] = bi;
        out[(size_t)IDX_OFF + n0 + t] = (float)bi;
    }
    __syncthreads();

    // ---- epilogue: gather e row, straight-through out, loss partial ----
    double lsum = 0.0;
    {
        const int p  = t & 63;
        const int cg = t >> 6;
        const int row = ldsI[p];
        const float* erow = emb + (size_t)row * DDIM;
        float* ob = out + (size_t)b * CHW + hw0 + p;
        for (int q = 0; q < 32; ++q) {
            const int c = cg * 32 + q;
            const float e  = erow[c];
            const float xx = xs[(size_t)c * HWSZ + p];
            const float diff = e - xx;             // fl(x_q - xt)
            ob[(size_t)c * HWSZ] = xx + diff;      // straight-through rounding
            lsum += (double)diff * (double)diff;
        }
    }
    #pragma unroll
    for (int off = 32; off > 0; off >>= 1)
        lsum += __shfl_xor(lsum, off);
    if ((t & 63) == 0) ldsL[t >> 6] = lsum;
    __syncthreads();
    if (t == 0) {
        double tot = 0.0;
        #pragma unroll
        for (int wv = 0; wv < 8; ++wv) tot += ldsL[wv];
        atomicAdd(&out[LOSS_OFF], (float)(tot * (1.25 / 4194304.0)));
    }
}

extern "C" void kernel_launch(void* const* d_in, const int* in_sizes, int n_in,
                              void* d_out, int out_size, void* d_ws, size_t ws_size,
                              hipStream_t stream) {
    (void)in_sizes; (void)n_in; (void)out_size; (void)ws_size;
    const float* x   = (const float*)d_in[0];
    const float* emb = (const float*)d_in[1];
    float* out = (float*)d_out;
    unsigned short* ehi = (unsigned short*)d_ws;
    unsigned short* elo = ehi + EHI_WORDS;
    float*          wse = (float*)((char*)d_ws + SE_OFF_B);
    hipMemsetAsync((char*)d_out + (size_t)LOSS_OFF * sizeof(float), 0, sizeof(float), stream);
    prep_kernel<<<256, 256, 0, stream>>>(emb, ehi, elo, wse);
    vq_kernel<<<NPTS / PTB, 512, 0, stream>>>(x, ehi, elo, wse, emb, out);
}